// Round 4
// baseline (13.542 us; speedup 1.0000x reference)
//
#include <hip/hip_runtime.h>

namespace {
constexpr float kEps = 1e-6f;
constexpr int kNPix = 90000;   // 300*300
constexpr int kBatch = 16;
constexpr int kPal = 30;
constexpr int kPixPerThread = 4;
constexpr int kTasksPerImg = kNPix / kPixPerThread;   // 22500
constexpr int kTotalTasks = kBatch * kTasksPerImg;    // 360000
constexpr int kBlock1 = 1024;
constexpr int kGrid1 = (kTotalTasks + kBlock1 - 1) / kBlock1;  // 352
constexpr int kBlock2 = 256;
constexpr double kInvSize = 1.0 / 4320000.0;          // 16*3*300*300
}  // namespace

// Stage 1: per-block partial sums of min-palette color distance.
// dist^2 + eps = (x^2+y^2+z^2) + min_p( -2a'x -2b'y -2c'z + (|a'|^2 + eps) )
// with a' = a - eps (folds the reference's "+EPS on diff").
__global__ __launch_bounds__(1024) void nps_partial_kernel(
    const float* __restrict__ patch, const float* __restrict__ pal,
    float* __restrict__ partial) {
  __shared__ float4 lpal[kPal];
  if (threadIdx.x < kPal) {
    const int p = threadIdx.x;
    const float a = pal[(p * 3 + 0) * kNPix] - kEps;
    const float b = pal[(p * 3 + 1) * kNPix] - kEps;
    const float c = pal[(p * 3 + 2) * kNPix] - kEps;
    lpal[p] = make_float4(-2.f * a, -2.f * b, -2.f * c,
                          fmaf(a, a, fmaf(b, b, fmaf(c, c, kEps))));
  }
  __syncthreads();

  float acc = 0.f;
  const int ti = blockIdx.x * kBlock1 + threadIdx.x;
  if (ti < kTotalTasks) {
    const int b = ti / kTasksPerImg;
    const int r = ti - b * kTasksPerImg;
    const float* base = patch + (size_t)b * (3 * kNPix) + r * kPixPerThread;
    const float4 vx = *reinterpret_cast<const float4*>(base);
    const float4 vy = *reinterpret_cast<const float4*>(base + kNPix);
    const float4 vz = *reinterpret_cast<const float4*>(base + 2 * kNPix);
    const float px[4] = {vx.x, vx.y, vx.z, vx.w};
    const float py[4] = {vy.x, vy.y, vy.z, vy.w};
    const float pz[4] = {vz.x, vz.y, vz.z, vz.w};

    float sx[4], md[4];
#pragma unroll
    for (int j = 0; j < 4; ++j) {
      sx[j] = fmaf(px[j], px[j], fmaf(py[j], py[j], pz[j] * pz[j]));
      md[j] = 3.4e38f;
    }
    // Palette in pairs: fminf(fminf(md,d0),d1) fuses to v_min3_f32.
#pragma unroll 3
    for (int p = 0; p < kPal; p += 2) {
      const float4 c0 = lpal[p];
      const float4 c1 = lpal[p + 1];
#pragma unroll
      for (int j = 0; j < 4; ++j) {
        const float d0 =
            fmaf(px[j], c0.x, fmaf(py[j], c0.y, fmaf(pz[j], c0.z, c0.w)));
        const float d1 =
            fmaf(px[j], c1.x, fmaf(py[j], c1.y, fmaf(pz[j], c1.z, c1.w)));
        md[j] = fminf(fminf(md[j], d0), d1);
      }
    }
#pragma unroll
    for (int j = 0; j < 4; ++j) acc += sqrtf(sx[j] + md[j]);
  }

  // Block reduction: wave shuffle, then LDS across the 16 waves.
#pragma unroll
  for (int off = 32; off > 0; off >>= 1) acc += __shfl_down(acc, off, 64);
  __shared__ float warp_sums[16];
  const int lane = threadIdx.x & 63;
  const int wid = threadIdx.x >> 6;
  if (lane == 0) warp_sums[wid] = acc;
  __syncthreads();
  if (wid == 0) {
    float s = (lane < 16) ? warp_sums[lane] : 0.f;
#pragma unroll
    for (int off = 8; off > 0; off >>= 1) s += __shfl_down(s, off, 64);
    if (lane == 0) partial[blockIdx.x] = s;
  }
}

// Stage 2: deterministic final reduction (single block), scale by 1/size.
__global__ __launch_bounds__(256) void nps_finish_kernel(
    const float* __restrict__ partial, int n, float* __restrict__ out) {
  double acc = 0.0;
  for (int i = threadIdx.x; i < n; i += kBlock2)
    acc += (double)partial[i];
#pragma unroll
  for (int off = 32; off > 0; off >>= 1) acc += __shfl_down(acc, off, 64);
  __shared__ double warp_sums[4];
  const int lane = threadIdx.x & 63;
  const int wid = threadIdx.x >> 6;
  if (lane == 0) warp_sums[wid] = acc;
  __syncthreads();
  if (threadIdx.x == 0)
    out[0] = (float)((warp_sums[0] + warp_sums[1] + warp_sums[2] +
                      warp_sums[3]) *
                     kInvSize);
}

extern "C" void kernel_launch(void* const* d_in, const int* in_sizes, int n_in,
                              void* d_out, int out_size, void* d_ws,
                              size_t ws_size, hipStream_t stream) {
  const float* patch = (const float*)d_in[0];  // [16,3,300,300] f32
  const float* pal = (const float*)d_in[1];    // [30,3,300,300] f32 (bcast colors)
  float* out = (float*)d_out;                  // scalar f32
  float* partial = (float*)d_ws;               // kGrid1 floats of scratch

  nps_partial_kernel<<<kGrid1, kBlock1, 0, stream>>>(patch, pal, partial);
  nps_finish_kernel<<<1, kBlock2, 0, stream>>>(partial, kGrid1, out);
}